// Round 13
// baseline (702.891 us; speedup 1.0000x reference)
//
#include <hip/hip_runtime.h>
#include <cstdint>
#include <cmath>

// Problem constants (fixed by reference):
//   B=64 examples, D=128 dim, NP=512 nodes/tokens per example, 100 Jacobi Sinkhorn iters.
#define NB_EX 64
#define DIMD 128
#define NP 512
constexpr float MARG = 1.0f / 512.0f;   // a = b = 1/n

// ---------- helpers ----------
__device__ __forceinline__ float bf2f_lo(unsigned w) { return __uint_as_float(w << 16); }
__device__ __forceinline__ float bf2f_hi(unsigned w) { return __uint_as_float(w & 0xFFFF0000u); }
__device__ __forceinline__ unsigned short f2bf(float f) {
    unsigned u = __float_as_uint(f);
    u += 0x7FFFu + ((u >> 16) & 1u);      // RTNE
    return (unsigned short)(u >> 16);
}
__device__ __forceinline__ float wred64(float v) {
#pragma unroll
    for (int m = 1; m < 64; m <<= 1) v += __shfl_xor(v, m, 64);
    return v;
}

// LDS-only workgroup barrier (R16, proven): __syncthreads() emits s_waitcnt vmcnt(0)
// lgkmcnt(0) before s_barrier, draining the fire-and-forget exchange stores (incl. the
// ~900cy agent/IF atomic) at EVERY barrier. The tag protocol never needs our own stores
// drained locally -> barrier only needs LDS ordering (lgkmcnt).
__device__ __forceinline__ void wg_barrier_lds() {
    __builtin_amdgcn_sched_barrier(0);
    asm volatile("s_waitcnt lgkmcnt(0)\n\ts_barrier" ::: "memory");
    __builtin_amdgcn_sched_barrier(0);
}

// Per-block dtype self-detection (bf16-pair low halfword exponent clusters in [110,130];
// fp32 low mantissa bits hit ~8%). 256-thread blocks only. Costs one syncthreads.
__device__ __forceinline__ int self_detect(const unsigned* probe, int t) {
    __shared__ int sd_cnt[4];
    unsigned w = probe[t];
    unsigned e = (w >> 7) & 0xFFu;
    unsigned long long m = __ballot(e >= 110u && e <= 130u);
    if ((t & 63) == 0) sd_cnt[t >> 6] = __popcll(m);
    __syncthreads();
    int c = sd_cnt[0] + sd_cnt[1] + sd_cnt[2] + sd_cnt[3];
    __syncthreads();
    return c >= 128;
}

// ---------- workspace layout (bytes) ----------
#define O_SIMG   0               // (unused -- global loss is on-chip since R22)
#define O_RNAN   16384           // 32768 f32 (131072)
#define O_RNBN   147456          // 32768 f32 (131072)
#define O_COLP   278528          // L2 copy: 2 chains x 2 banks x 64ex x 4blk x 512 u32 (2 MB)
#define O_COLPIF 2375680         // IF copy: same shape (2 MB) -> both fit the old 4 MB window
#define O_P0     4472832         // 64*512*512 bf16 (33554432) -> total ~38 MB (proven fit)

// ---------- fused inverse L2 norms for struct_nodes + seq_tokens (65536 rows) ----------
// (R21-proven parallel producer.)
__global__ void k_rnormAB(const void* anr, const void* bnr, float* rnan, float* rnbn) {
    int t = threadIdx.x;
    int flag = self_detect((const unsigned*)anr, t);
    int gr  = blockIdx.x * 4 + (t >> 6);      // global row 0..65535
    int lane = t & 63;
    const void* in = (gr < 32768) ? anr : bnr;
    float* rn      = (gr < 32768) ? rnan : rnbn;
    int row = gr & 32767;
    float f0, f1;
    if (flag) {
        unsigned w = ((const unsigned*)in)[row * 64 + lane];
        f0 = bf2f_lo(w); f1 = bf2f_hi(w);
    } else {
        float2 v = ((const float2*)in)[row * 64 + lane];
        f0 = v.x; f1 = v.y;
    }
    float ss = wred64(f0 * f0 + f1 * f1);
    if (lane == 0) rn[row] = 1.0f / fmaxf(sqrtf(ss), 1e-12f);
}

// ---------- R24: k_build with transposed LDS tiles + embedded global-loss block ----------
// Grid (17, 64). Blocks x<16: fp32 SMEM GEMM -> exp -> bf16 P0. R24 change: staging
// tiles are stored kk-major (Ast[32][132], Bst[32][132] -- same 33792B arena as before,
// occupancy unchanged) so the inner loop's av/bv gathers become 2+2 ds_read_b128 of
// contiguous floats (av addresses are 4-per-wave broadcasts; bv at worst 4-way conflict)
// instead of 16 strided ds_read_b32. FMA sequence per acc[i][j] is identical
// value-for-value and order-for-order -> bit-identical P0 (absmax 0.0 by construction).
// Write side: 8 scattered b32/thread/kc (4-way conflict) -- negligible vs 512 reads.
// Block (16,0): the R22/R23-proven fused sim+gloss body (verbatim). Blocks (16,y>0) exit.
__global__ void k_build_g(const void* anr, const void* bnr,
                          const float* rnan, const float* rnbn,
                          const void* sgr, const void* qgr,
                          unsigned short* p0, float* outf) {
    __shared__ __align__(16) char smem[2 * 32 * 132 * 4];   // 33792 B arena (same size)
    int t = threadIdx.x;

    if (blockIdx.x == 16) {
        if (blockIdx.y != 0) return;
        // ---- fused global NT-Xent (R22/R23-proven body, verbatim arithmetic) ----
        float* rls    = (float*)smem;                 // 128 f32
        float* simg_s = (float*)(smem + 512);         // 4096 f32
        float* red    = (float*)(smem + 512 + 16384); // 64 f32
        int flag = self_detect((const unsigned*)sgr, t);
        int w = t >> 6, lane = t & 63;
        for (int rr = 0; rr < 32; rr++) {             // each wave: 32 of 128 rows
            int ri = w * 32 + rr;
            const void* base = (ri < 64) ? sgr : qgr;
            int row = ri & 63;
            float f0, f1;
            if (flag) {
                unsigned wd = ((const unsigned*)base)[row * 64 + lane];
                f0 = bf2f_lo(wd); f1 = bf2f_hi(wd);
            } else {
                float2 v = ((const float2*)base)[row * 64 + lane];
                f0 = v.x; f1 = v.y;
            }
            float ss = wred64(f0 * f0 + f1 * f1);
            if (lane == 0) rls[ri] = 1.0f / fmaxf(sqrtf(ss), 1e-12f);
        }
        __syncthreads();
        for (int n = 0; n < 16; n++) {                // 4096 = 16 x 256
            int g = n * 256 + t;
            int i = g >> 6, j = g & 63;
            float dot = 0.f;
            if (flag) {
                const unsigned* a = (const unsigned*)sgr + i * 64;
                const unsigned* b = (const unsigned*)qgr + j * 64;
                for (int k = 0; k < 64; k++) {
                    unsigned wa = a[k], wb = b[k];
                    dot += bf2f_lo(wa) * bf2f_lo(wb);
                    dot += bf2f_hi(wa) * bf2f_hi(wb);
                }
            } else {
                const float4* a = (const float4*)sgr + i * 32;
                const float4* b = (const float4*)qgr + j * 32;
                for (int k = 0; k < 32; k++) {
                    float4 x = a[k], y = b[k];
                    dot += x.x * y.x + x.y * y.y + x.z * y.z + x.w * y.w;
                }
            }
            simg_s[g] = dot * rls[i] * rls[64 + j] * 10.0f;   // /TEMP = *10
        }
        __syncthreads();
        int i = t;
        if (i < 64) {
            float m = -1e30f;
            for (int j = 0; j < 64; j++) m = fmaxf(m, simg_s[i * 64 + j]);
            float se = 0.f;
            for (int j = 0; j < 64; j++) se += expf(simg_s[i * 64 + j] - m);
            float rl = simg_s[i * 64 + i] - (m + logf(se));
            float m2 = -1e30f;
            for (int j = 0; j < 64; j++) m2 = fmaxf(m2, simg_s[j * 64 + i]);
            float se2 = 0.f;
            for (int j = 0; j < 64; j++) se2 += expf(simg_s[j * 64 + i] - m2);
            float cl = simg_s[i * 64 + i] - (m2 + logf(se2));
            red[i] = rl + cl;
        }
        __syncthreads();
        if (i == 0) {
            float s = 0.f;
            for (int k = 0; k < 64; k++) s += red[k];
            float g = -s / 128.0f;
            outf[0] = g;          // global loss
            outf[1] = 0.0f;       // local loss accumulated by k_persist
            outf[2] = g;          // total = g + local (added by k_persist)
        }
        return;
    }

    // ---- build body: transposed staging (Ast[kk][row]), verbatim FMA order ----
    float (*Ast)[132] = (float(*)[132])smem;                    // 32 x 132 f32 (16896 B)
    float (*Bst)[132] = (float(*)[132])(smem + 32 * 132 * 4);   // 32 x 132 f32
    int flag = self_detect((const unsigned*)anr, t);
    int b   = blockIdx.y;
    int r0t = (blockIdx.x >> 2) * 128;
    int c0t = (blockIdx.x & 3) * 128;
    int tr = t >> 4, tc = t & 15;
    float acc[8][8];
#pragma unroll
    for (int i = 0; i < 8; i++)
#pragma unroll
        for (int j = 0; j < 8; j++) acc[i][j] = 0.f;

    for (int kc = 0; kc < 4; kc++) {            // K chunks of 32
        for (int ii = 0; ii < 4; ii++) {
            int idx = t + 256 * ii;             // 0..1023 -> 128 rows x 8 float4
            int r = idx >> 3, c4 = idx & 7;
            {   // A chunk (struct_nodes): old As[r][c4*4+k] -> Ast[c4*4+k][r]
                int grow = b * NP + r0t + r;
                float sc = rnan[grow];
                float f0, f1, f2, f3;
                if (flag) {
                    const unsigned* src = (const unsigned*)anr + ((grow * DIMD + kc * 32 + c4 * 4) >> 1);
                    unsigned w0 = src[0], w1 = src[1];
                    f0 = bf2f_lo(w0); f1 = bf2f_hi(w0); f2 = bf2f_lo(w1); f3 = bf2f_hi(w1);
                } else {
                    float4 v = *((const float4*)((const float*)anr + grow * DIMD + kc * 32 + c4 * 4));
                    f0 = v.x; f1 = v.y; f2 = v.z; f3 = v.w;
                }
                Ast[c4 * 4 + 0][r] = f0 * sc; Ast[c4 * 4 + 1][r] = f1 * sc;
                Ast[c4 * 4 + 2][r] = f2 * sc; Ast[c4 * 4 + 3][r] = f3 * sc;
            }
            {   // B chunk (seq_tokens): old Bs[r][c4*4+k] -> Bst[c4*4+k][r]
                int grow = b * NP + c0t + r;
                float sc = rnbn[grow];
                float f0, f1, f2, f3;
                if (flag) {
                    const unsigned* src = (const unsigned*)bnr + ((grow * DIMD + kc * 32 + c4 * 4) >> 1);
                    unsigned w0 = src[0], w1 = src[1];
                    f0 = bf2f_lo(w0); f1 = bf2f_hi(w0); f2 = bf2f_lo(w1); f3 = bf2f_hi(w1);
                } else {
                    float4 v = *((const float4*)((const float*)bnr + grow * DIMD + kc * 32 + c4 * 4));
                    f0 = v.x; f1 = v.y; f2 = v.z; f3 = v.w;
                }
                Bst[c4 * 4 + 0][r] = f0 * sc; Bst[c4 * 4 + 1][r] = f1 * sc;
                Bst[c4 * 4 + 2][r] = f2 * sc; Bst[c4 * 4 + 3][r] = f3 * sc;
            }
        }
        __syncthreads();
        for (int kk = 0; kk < 32; kk++) {
            // av[i] = old As[tr*8+i][kk] = Ast[kk][tr*8+i] -> 2 contiguous float4 loads
            float4 a0 = *(const float4*)&Ast[kk][tr * 8];
            float4 a1 = *(const float4*)&Ast[kk][tr * 8 + 4];
            float4 b0 = *(const float4*)&Bst[kk][tc * 8];
            float4 b1 = *(const float4*)&Bst[kk][tc * 8 + 4];
            float av[8] = {a0.x, a0.y, a0.z, a0.w, a1.x, a1.y, a1.z, a1.w};
            float bv[8] = {b0.x, b0.y, b0.z, b0.w, b1.x, b1.y, b1.z, b1.w};
#pragma unroll
            for (int i = 0; i < 8; i++)
#pragma unroll
                for (int j = 0; j < 8; j++) acc[i][j] += av[i] * bv[j];
        }
        __syncthreads();
    }
#pragma unroll
    for (int i = 0; i < 8; i++) {
        int grow = b * NP + r0t + tr * 8 + i;
        unsigned short h[8];
#pragma unroll
        for (int j = 0; j < 8; j++) h[j] = f2bf(expf(acc[i][j] * 10.0f));   // exp(sim/REG)
        uint4 pk;
        pk.x = (unsigned)h[0] | ((unsigned)h[1] << 16);
        pk.y = (unsigned)h[2] | ((unsigned)h[3] << 16);
        pk.z = (unsigned)h[4] | ((unsigned)h[5] << 16);
        pk.w = (unsigned)h[6] | ((unsigned)h[7] << 16);
        *((uint4*)(p0 + ((size_t)grow * NP + c0t + tc * 8))) = pk;
    }
}

// ---------- exchange primitives ----------
// Dual-write: plain store -> lands in this XCD's L2 (fast path for same-XCD partners);
// agent-scope relaxed atomic -> Infinity Cache (the proven, placement-independent path).
__device__ __forceinline__ void store_dual(unsigned* l2p, unsigned* ifp, unsigned v) {
    *l2p = v;
    __hip_atomic_store(ifp, v, __ATOMIC_RELAXED, __HIP_MEMORY_SCOPE_AGENT);
}

// R12 batched polling (proven): all 8 sc0 loads issue back-to-back in ONE asm block with
// ONE waitcnt -> a round costs ~1 L2 latency. One SGPR base, one VGPR voffset = t*4+4096
// (centered), partner stride 2048B / col1 +1024B folded into 13-bit signed immediates.
// Mask-free termination: matched slots re-match (write-once per (bank,chain,slot,tag)).
// From round 2 on, additionally batch-poll the IF copy (placement-independent fallback).
__device__ __forceinline__ void poll_sums(const unsigned* crdL2, const unsigned* crdIF,
                                          unsigned tag, int t, float& r0, float& r1) {
    unsigned voff = (unsigned)(t * 4) + 4096u;
    unsigned q0, q1, q2, q3, q4, q5, q6, q7;
    for (int round = 0;; ++round) {
        asm volatile(
            "global_load_dword %0, %8, %9 offset:-4096 sc0\n\t"
            "global_load_dword %1, %8, %9 offset:-2048 sc0\n\t"
            "global_load_dword %2, %8, %9 offset:0 sc0\n\t"
            "global_load_dword %3, %8, %9 offset:2048 sc0\n\t"
            "global_load_dword %4, %8, %9 offset:-3072 sc0\n\t"
            "global_load_dword %5, %8, %9 offset:-1024 sc0\n\t"
            "global_load_dword %6, %8, %9 offset:1024 sc0\n\t"
            "global_load_dword %7, %8, %9 offset:3072 sc0\n\t"
            "s_waitcnt vmcnt(0)"
            : "=&v"(q0), "=&v"(q1), "=&v"(q2), "=&v"(q3),
              "=&v"(q4), "=&v"(q5), "=&v"(q6), "=&v"(q7)
            : "v"(voff), "s"(crdL2)
            : "memory");
        if (round >= 2) {
            // IF fallback copy, batched (8 independent agent loads, compiler-coalesced waits)
            const unsigned* pp = crdIF + t;
            unsigned b0 = __hip_atomic_load(pp +    0, __ATOMIC_RELAXED, __HIP_MEMORY_SCOPE_AGENT);
            unsigned b1 = __hip_atomic_load(pp +  512, __ATOMIC_RELAXED, __HIP_MEMORY_SCOPE_AGENT);
            unsigned b2 = __hip_atomic_load(pp + 1024, __ATOMIC_RELAXED, __HIP_MEMORY_SCOPE_AGENT);
            unsigned b3 = __hip_atomic_load(pp + 1536, __ATOMIC_RELAXED, __HIP_MEMORY_SCOPE_AGENT);
            unsigned b4 = __hip_atomic_load(pp +  256, __ATOMIC_RELAXED, __HIP_MEMORY_SCOPE_AGENT);
            unsigned b5 = __hip_atomic_load(pp +  768, __ATOMIC_RELAXED, __HIP_MEMORY_SCOPE_AGENT);
            unsigned b6 = __hip_atomic_load(pp + 1280, __ATOMIC_RELAXED, __HIP_MEMORY_SCOPE_AGENT);
            unsigned b7 = __hip_atomic_load(pp + 1792, __ATOMIC_RELAXED, __HIP_MEMORY_SCOPE_AGENT);
            if ((q0 & 0xFFFFu) != tag) q0 = b0;
            if ((q1 & 0xFFFFu) != tag) q1 = b1;
            if ((q2 & 0xFFFFu) != tag) q2 = b2;
            if ((q3 & 0xFFFFu) != tag) q3 = b3;
            if ((q4 & 0xFFFFu) != tag) q4 = b4;
            if ((q5 & 0xFFFFu) != tag) q5 = b5;
            if ((q6 & 0xFFFFu) != tag) q6 = b6;
            if ((q7 & 0xFFFFu) != tag) q7 = b7;
        }
        bool ok = ((q0 & 0xFFFFu) == tag) && ((q1 & 0xFFFFu) == tag)
               && ((q2 & 0xFFFFu) == tag) && ((q3 & 0xFFFFu) == tag)
               && ((q4 & 0xFFFFu) == tag) && ((q5 & 0xFFFFu) == tag)
               && ((q6 & 0xFFFFu) == tag) && ((q7 & 0xFFFFu) == tag);
        if (ok) break;
        if (round >= 2) __builtin_amdgcn_s_sleep(1);
    }
    r0 = __uint_as_float(q0 & 0xFFFF0000u) + __uint_as_float(q1 & 0xFFFF0000u)
       + __uint_as_float(q2 & 0xFFFF0000u) + __uint_as_float(q3 & 0xFFFF0000u);
    r1 = __uint_as_float(q4 & 0xFFFF0000u) + __uint_as_float(q5 & 0xFFFF0000u)
       + __uint_as_float(q6 & 0xFFFF0000u) + __uint_as_float(q7 & 0xFFFF0000u);
}

// ---------- persistent Sinkhorn: dual-chain, 4 blocks/example, XCD-local fast exchange ----------
// R16 structure verbatim (proven ~430us k_persist, absmax 0.0): (a) lgkmcnt-only barriers;
// (b) barriers B/D removed (audit: credU w->A->r; credV,v_sU w->C->r; v_sV w->next-A->r;
// u_s* wave-local; rewrites separated by a full barrier); (c) R12 batched 8-load
// single-waitcnt poll. Schedule per double-step: colU;A; storeU+rowV; colV; pollU;C;
// storeV+rowU; pollV. Mod-2 banks per chain. Tags 1..50; 0xAA-poisoned stale ws (0xAAAA)
// never matches a tag.
__global__ __launch_bounds__(256, 1) void k_persist(const unsigned short* __restrict__ p0,
                                                    unsigned* __restrict__ colpL2,
                                                    unsigned* __restrict__ colpIF,
                                                    float* __restrict__ outf) {
    int blk = blockIdx.x;
    int rb  = blk >> 6;         // 0..3 (partners differ by 64 in blk -> same blk%8 -> same XCD)
    int b   = blk & 63;         // example
    int rowbase = rb * 128;
    int t = threadIdx.x, w = t >> 6, lane = t & 63;

    __shared__ float credU[4][512];
    __shared__ float credV[4][512];
    __shared__ float v_sU[512];
    __shared__ float v_sV[512];
    __shared__ float u_sU[128];
    __shared__ float u_sV[128];
    __shared__ float bs[4];

    // this lane's static P0 slice: 32 rows x 8 cols packed bf16 = 128 VGPRs
    uint4 pw[32];
#pragma unroll
    for (int r = 0; r < 32; r++) {
        int row = rowbase + w * 32 + r;
        pw[r] = ((const uint4*)(p0 + (((size_t)(b << 9) + row) << 9)))[lane];
    }
    int col0 = t, col1 = t + 256;
    if (t < 128) u_sU[t] = MARG;                   // u_0 = a
    v_sV[col0] = MARG; v_sV[col1] = MARG;          // v_0 = b
    __syncthreads();

#pragma unroll 1
    for (int s = 0; s < 50; ++s) {
        unsigned tag = (unsigned)(s + 1);
        int bank = s & 1;
        // ---- 1. col pass chain U ----
        {
            float ca[8];
#pragma unroll
            for (int k = 0; k < 8; ++k) ca[k] = 0.f;
#pragma unroll
            for (int r = 0; r < 32; ++r) {
                float u_r = u_sU[w * 32 + r];
                uint4 pv = pw[r];
                ca[0] += bf2f_lo(pv.x) * u_r; ca[1] += bf2f_hi(pv.x) * u_r;
                ca[2] += bf2f_lo(pv.y) * u_r; ca[3] += bf2f_hi(pv.y) * u_r;
                ca[4] += bf2f_lo(pv.z) * u_r; ca[5] += bf2f_hi(pv.z) * u_r;
                ca[6] += bf2f_lo(pv.w) * u_r; ca[7] += bf2f_hi(pv.w) * u_r;
            }
#pragma unroll
            for (int k = 0; k < 8; ++k) credU[w][lane * 8 + k] = ca[k];
        }
        wg_barrier_lds();   // A
        // ---- 2. store U (dual, fire-and-forget), then rowpass V (local) ----
        {
            int slot = ((bank * 64 + b) * 4 + rb) << 9;                  // chain U
            float s0 = credU[0][col0] + credU[1][col0] + credU[2][col0] + credU[3][col0];
            float s1 = credU[0][col1] + credU[1][col1] + credU[2][col1] + credU[3][col1];
            store_dual(colpL2 + slot + col0, colpIF + slot + col0,
                       ((unsigned)f2bf(s0) << 16) | tag);
            store_dual(colpL2 + slot + col1, colpIF + slot + col1,
                       ((unsigned)f2bf(s1) << 16) | tag);
        }
        {   // rowpass V: u'_{2s+1} = a/(P0 v_2s) -> u_sV (wave-local)
            float vr[8];
#pragma unroll
            for (int k = 0; k < 8; ++k) vr[k] = v_sV[lane * 8 + k];
#pragma unroll
            for (int g = 0; g < 4; ++g) {
                float rp[8];
#pragma unroll
                for (int j = 0; j < 8; ++j) {
                    uint4 pv = pw[g * 8 + j];
                    rp[j] = bf2f_lo(pv.x) * vr[0] + bf2f_hi(pv.x) * vr[1]
                          + bf2f_lo(pv.y) * vr[2] + bf2f_hi(pv.y) * vr[3]
                          + bf2f_lo(pv.z) * vr[4] + bf2f_hi(pv.z) * vr[5]
                          + bf2f_lo(pv.w) * vr[6] + bf2f_hi(pv.w) * vr[7];
                }
#pragma unroll
                for (int m = 1; m < 64; m <<= 1)
#pragma unroll
                    for (int j = 0; j < 8; ++j) rp[j] += __shfl_xor(rp[j], m, 64);
                float sel = rp[0];
#pragma unroll
                for (int j = 1; j < 8; ++j) if (lane == j) sel = rp[j];
                if (lane < 8) {
                    float q = MARG / sel;
                    if (!isfinite(q)) q = MARG;
                    u_sV[w * 32 + g * 8 + lane] = q;
                }
            }
        }
        // ---- 3. col pass chain V ----
        {
            float ca[8];
#pragma unroll
            for (int k = 0; k < 8; ++k) ca[k] = 0.f;
#pragma unroll
            for (int r = 0; r < 32; ++r) {
                float u_r = u_sV[w * 32 + r];      // same-wave RAW, lgkmcnt only
                uint4 pv = pw[r];
                ca[0] += bf2f_lo(pv.x) * u_r; ca[1] += bf2f_hi(pv.x) * u_r;
                ca[2] += bf2f_lo(pv.y) * u_r; ca[3] += bf2f_hi(pv.y) * u_r;
                ca[4] += bf2f_lo(pv.z) * u_r; ca[5] += bf2f_hi(pv.z) * u_r;
                ca[6] += bf2f_lo(pv.w) * u_r; ca[7] += bf2f_hi(pv.w) * u_r;
            }
#pragma unroll
            for (int k = 0; k < 8; ++k) credV[w][lane * 8 + k] = ca[k];
        }
        // (barrier B removed: credV/v_sU readers are all behind barrier C)
        // ---- 4. poll chain U -> v_sU ----
        {
            int base = ((bank * 64 + b) * 4) << 9;                       // chain U
            float r0, r1;
            poll_sums(colpL2 + base, colpIF + base, tag, t, r0, r1);
            float q0 = MARG / r0; if (!isfinite(q0)) q0 = MARG;
            float q1 = MARG / r1; if (!isfinite(q1)) q1 = MARG;
            v_sU[col0] = q0;
            v_sU[col1] = q1;
        }
        wg_barrier_lds();   // C
        // ---- 5. store V (dual), then rowpass U (local) ----
        {
            int slot = (((2 + bank) * 64 + b) * 4 + rb) << 9;            // chain V
            float s0 = credV[0][col0] + credV[1][col0] + credV[2][col0] + credV[3][col0];
            float s1 = credV[0][col1] + credV[1][col1] + credV[2][col1] + credV[3][col1];
            store_dual(colpL2 + slot + col0, colpIF + slot + col0,
                       ((unsigned)f2bf(s0) << 16) | tag);
            store_dual(colpL2 + slot + col1, colpIF + slot + col1,
                       ((unsigned)f2bf(s1) << 16) | tag);
        }
        {   // rowpass U: u_{2s+2} = a/(P0 v'_{2s+1}) -> u_sU (wave-local)
            float vr[8];
#pragma unroll
            for (int k = 0; k < 8; ++k) vr[k] = v_sU[lane * 8 + k];
#pragma unroll
            for (int g = 0; g < 4; ++g) {
                float rp[8];
#pragma unroll
                for (int j = 0; j < 8; ++j) {
                    uint4 pv = pw[g * 8 + j];
                    rp[j] = bf2f_lo(pv.x) * vr[0] + bf2f_hi(pv.x) * vr[1]
                          + bf2f_lo(pv.y) * vr[2] + bf2f_hi(pv.y) * vr[3]
                          + bf2f_lo(pv.z) * vr[4] + bf2f_hi(pv.z) * vr[5]
                          + bf2f_lo(pv.w) * vr[6] + bf2f_hi(pv.w) * vr[7];
                }
#pragma unroll
                for (int m = 1; m < 64; m <<= 1)
#pragma unroll
                    for (int j = 0; j < 8; ++j) rp[j] += __shfl_xor(rp[j], m, 64);
                float sel = rp[0];
#pragma unroll
                for (int j = 1; j < 8; ++j) if (lane == j) sel = rp[j];
                if (lane < 8) {
                    float q = MARG / sel;
                    if (!isfinite(q)) q = MARG;
                    u_sU[w * 32 + g * 8 + lane] = q;
                }
            }
        }
        // ---- 6. poll chain V -> v_sV ----
        {
            int base = (((2 + bank) * 64 + b) * 4) << 9;                 // chain V
            float r0, r1;
            poll_sums(colpL2 + base, colpIF + base, tag, t, r0, r1);
            float q0 = MARG / r0; if (!isfinite(q0)) q0 = MARG;
            float q1 = MARG / r1; if (!isfinite(q1)) q1 = MARG;
            v_sV[col0] = q0;
            v_sV[col1] = q1;
        }
        // (barrier D removed: v_sV readers are behind next iteration's barrier A,
        //  or the post-loop barrier below)
    }
    wg_barrier_lds();   // post-loop: v_sV cross-thread reads in the final contraction

    // ---- final contraction: u_100 (u_sU) x v_100 (v_sV) ; C = -0.1*log(P0) ----
    float vr[8];
#pragma unroll
    for (int k = 0; k < 8; ++k) vr[k] = v_sV[lane * 8 + k];
    float acc = 0.f;
#pragma unroll
    for (int r = 0; r < 32; ++r) {
        float u_r = u_sU[w * 32 + r];
        uint4 pv = pw[r];
        float f[8];
        f[0] = bf2f_lo(pv.x); f[1] = bf2f_hi(pv.x);
        f[2] = bf2f_lo(pv.y); f[3] = bf2f_hi(pv.y);
        f[4] = bf2f_lo(pv.z); f[5] = bf2f_hi(pv.z);
        f[6] = bf2f_lo(pv.w); f[7] = bf2f_hi(pv.w);
#pragma unroll
        for (int k = 0; k < 8; ++k) {
            float p = f[k];
            acc += u_r * p * vr[k] * (-0.1f) * logf(p);
        }
    }
    acc = wred64(acc);
    if (lane == 0) bs[w] = acc;
    __syncthreads();
    if (t == 0) {
        float c = (bs[0] + bs[1] + bs[2] + bs[3]) * (1.0f / 64.0f);   // /B
        atomicAdd(&outf[1], c);
        atomicAdd(&outf[2], c);
    }
}

extern "C" void kernel_launch(void* const* d_in, const int* in_sizes, int n_in,
                              void* d_out, int out_size, void* d_ws, size_t ws_size,
                              hipStream_t stream) {
    const void* sg = d_in[0];
    const void* qg = d_in[1];
    const void* an = d_in[2];
    const void* bn = d_in[3];
    char* ws = (char*)d_ws;
    float* outf = (float*)d_out;                     // output dtype: float32 x3

    float* rnan      = (float*)(ws + O_RNAN);
    float* rnbn      = (float*)(ws + O_RNBN);
    unsigned* colpL2 = (unsigned*)(ws + O_COLP);     // L2-resident tagged copy
    unsigned* colpIF = (unsigned*)(ws + O_COLPIF);   // IF-resident tagged copy (fallback)
    unsigned short* p0 = (unsigned short*)(ws + O_P0);

    // R24: 3 launches. k_rnormAB -> k_build_g (transposed-LDS build + embedded
    // global-loss block) -> k_persist (R16-proven).
    k_rnormAB<<<16384, 256, 0, stream>>>(an, bn, rnan, rnbn);
    k_build_g<<<dim3(17, 64), 256, 0, stream>>>(an, bn, rnan, rnbn, sg, qg, p0, outf);
    k_persist<<<256, 256, 0, stream>>>(p0, colpL2, colpIF, outf);
}

// Round 14
// 613.262 us; speedup vs baseline: 1.1462x; 1.1462x over previous
//
#include <hip/hip_runtime.h>
#include <cstdint>
#include <cmath>

// Problem constants (fixed by reference):
//   B=64 examples, D=128 dim, NP=512 nodes/tokens per example, 100 Jacobi Sinkhorn iters.
#define NB_EX 64
#define DIMD 128
#define NP 512
constexpr float MARG = 1.0f / 512.0f;   // a = b = 1/n

// ---------- helpers ----------
__device__ __forceinline__ float bf2f_lo(unsigned w) { return __uint_as_float(w << 16); }
__device__ __forceinline__ float bf2f_hi(unsigned w) { return __uint_as_float(w & 0xFFFF0000u); }
__device__ __forceinline__ unsigned short f2bf(float f) {
    unsigned u = __float_as_uint(f);
    u += 0x7FFFu + ((u >> 16) & 1u);      // RTNE
    return (unsigned short)(u >> 16);
}
__device__ __forceinline__ float wred64(float v) {
#pragma unroll
    for (int m = 1; m < 64; m <<= 1) v += __shfl_xor(v, m, 64);
    return v;
}

// LDS-only workgroup barrier (R16, proven): __syncthreads() emits s_waitcnt vmcnt(0)
// lgkmcnt(0) before s_barrier, draining the fire-and-forget exchange stores (incl. the
// ~900cy agent/IF atomic) at EVERY barrier. The tag protocol never needs our own stores
// drained locally -> barrier only needs LDS ordering (lgkmcnt).
__device__ __forceinline__ void wg_barrier_lds() {
    __builtin_amdgcn_sched_barrier(0);
    asm volatile("s_waitcnt lgkmcnt(0)\n\ts_barrier" ::: "memory");
    __builtin_amdgcn_sched_barrier(0);
}

// Per-block dtype self-detection (bf16-pair low halfword exponent clusters in [110,130];
// fp32 low mantissa bits hit ~8%). 256-thread blocks only. Costs one syncthreads.
__device__ __forceinline__ int self_detect(const unsigned* probe, int t) {
    __shared__ int sd_cnt[4];
    unsigned w = probe[t];
    unsigned e = (w >> 7) & 0xFFu;
    unsigned long long m = __ballot(e >= 110u && e <= 130u);
    if ((t & 63) == 0) sd_cnt[t >> 6] = __popcll(m);
    __syncthreads();
    int c = sd_cnt[0] + sd_cnt[1] + sd_cnt[2] + sd_cnt[3];
    __syncthreads();
    return c >= 128;
}

// ---------- workspace layout (bytes) ----------
#define O_SIMG   0               // (unused -- global loss is on-chip since R22)
#define O_RNAN   16384           // 32768 f32 (131072)
#define O_RNBN   147456          // 32768 f32 (131072)
#define O_COLP   278528          // L2 copy: 2 chains x 2 banks x 64ex x 4blk x 512 u32 (2 MB)
#define O_COLPIF 2375680         // IF copy: same shape (2 MB) -> both fit the old 4 MB window
#define O_P0     4472832         // 64*512*512 bf16 (33554432) -> total ~38 MB (proven fit)

// ---------- fused inverse L2 norms for struct_nodes + seq_tokens (65536 rows) ----------
// (R21-proven parallel producer.)
__global__ void k_rnormAB(const void* anr, const void* bnr, float* rnan, float* rnbn) {
    int t = threadIdx.x;
    int flag = self_detect((const unsigned*)anr, t);
    int gr  = blockIdx.x * 4 + (t >> 6);      // global row 0..65535
    int lane = t & 63;
    const void* in = (gr < 32768) ? anr : bnr;
    float* rn      = (gr < 32768) ? rnan : rnbn;
    int row = gr & 32767;
    float f0, f1;
    if (flag) {
        unsigned w = ((const unsigned*)in)[row * 64 + lane];
        f0 = bf2f_lo(w); f1 = bf2f_hi(w);
    } else {
        float2 v = ((const float2*)in)[row * 64 + lane];
        f0 = v.x; f1 = v.y;
    }
    float ss = wred64(f0 * f0 + f1 * f1);
    if (lane == 0) rn[row] = 1.0f / fmaxf(sqrtf(ss), 1e-12f);
}

// ---------- R23 (proven best, 613.6us total): k_build + embedded global-loss block ----------
// Grid (17, 64). Blocks x<16: the R21-proven fp32 SMEM GEMM -> exp -> bf16 P0 (verbatim
// arithmetic, row-major As/Bs tiles -- R24's transposed tiles were neutral-to-negative).
// Block (16,0): the R22-proven fused sim+gloss body (verbatim; absmax 0.0) -- runs
// CONCURRENTLY under the build grid instead of as two serial launches. Blocks (16, y>0)
// exit. LDS: manual overlay arena sized for the build role (33.8 KB) so build occupancy
// (~4 blocks/CU) is unchanged; the global-loss role uses 17.2 KB of the arena.
__global__ void k_build_g(const void* anr, const void* bnr,
                          const float* rnan, const float* rnbn,
                          const void* sgr, const void* qgr,
                          unsigned short* p0, float* outf) {
    __shared__ __align__(16) char smem[2 * 128 * 33 * 4];   // 33792 B arena
    int t = threadIdx.x;

    if (blockIdx.x == 16) {
        if (blockIdx.y != 0) return;
        // ---- fused global NT-Xent (R22-proven body, verbatim arithmetic) ----
        float* rls    = (float*)smem;               // 128 f32
        float* simg_s = (float*)(smem + 512);       // 4096 f32
        float* red    = (float*)(smem + 512 + 16384); // 64 f32
        int flag = self_detect((const unsigned*)sgr, t);
        int w = t >> 6, lane = t & 63;
        for (int rr = 0; rr < 32; rr++) {           // each wave: 32 of 128 rows
            int ri = w * 32 + rr;
            const void* base = (ri < 64) ? sgr : qgr;
            int row = ri & 63;
            float f0, f1;
            if (flag) {
                unsigned wd = ((const unsigned*)base)[row * 64 + lane];
                f0 = bf2f_lo(wd); f1 = bf2f_hi(wd);
            } else {
                float2 v = ((const float2*)base)[row * 64 + lane];
                f0 = v.x; f1 = v.y;
            }
            float ss = wred64(f0 * f0 + f1 * f1);
            if (lane == 0) rls[ri] = 1.0f / fmaxf(sqrtf(ss), 1e-12f);
        }
        __syncthreads();
        for (int n = 0; n < 16; n++) {              // 4096 = 16 x 256
            int g = n * 256 + t;
            int i = g >> 6, j = g & 63;
            float dot = 0.f;
            if (flag) {
                const unsigned* a = (const unsigned*)sgr + i * 64;
                const unsigned* b = (const unsigned*)qgr + j * 64;
                for (int k = 0; k < 64; k++) {
                    unsigned wa = a[k], wb = b[k];
                    dot += bf2f_lo(wa) * bf2f_lo(wb);
                    dot += bf2f_hi(wa) * bf2f_hi(wb);
                }
            } else {
                const float4* a = (const float4*)sgr + i * 32;
                const float4* b = (const float4*)qgr + j * 32;
                for (int k = 0; k < 32; k++) {
                    float4 x = a[k], y = b[k];
                    dot += x.x * y.x + x.y * y.y + x.z * y.z + x.w * y.w;
                }
            }
            simg_s[g] = dot * rls[i] * rls[64 + j] * 10.0f;   // /TEMP = *10
        }
        __syncthreads();
        int i = t;
        if (i < 64) {
            float m = -1e30f;
            for (int j = 0; j < 64; j++) m = fmaxf(m, simg_s[i * 64 + j]);
            float se = 0.f;
            for (int j = 0; j < 64; j++) se += expf(simg_s[i * 64 + j] - m);
            float rl = simg_s[i * 64 + i] - (m + logf(se));
            float m2 = -1e30f;
            for (int j = 0; j < 64; j++) m2 = fmaxf(m2, simg_s[j * 64 + i]);
            float se2 = 0.f;
            for (int j = 0; j < 64; j++) se2 += expf(simg_s[j * 64 + i] - m2);
            float cl = simg_s[i * 64 + i] - (m2 + logf(se2));
            red[i] = rl + cl;
        }
        __syncthreads();
        if (i == 0) {
            float s = 0.f;
            for (int k = 0; k < 64; k++) s += red[k];
            float g = -s / 128.0f;
            outf[0] = g;          // global loss
            outf[1] = 0.0f;       // local loss accumulated by k_persist
            outf[2] = g;          // total = g + local (added by k_persist)
        }
        return;
    }

    // ---- R21-proven build body (verbatim arithmetic; As/Bs carved from the arena) ----
    float (*As)[33] = (float(*)[33])smem;
    float (*Bs)[33] = (float(*)[33])(smem + 128 * 33 * 4);
    int flag = self_detect((const unsigned*)anr, t);
    int b   = blockIdx.y;
    int r0t = (blockIdx.x >> 2) * 128;
    int c0t = (blockIdx.x & 3) * 128;
    int tr = t >> 4, tc = t & 15;
    float acc[8][8];
#pragma unroll
    for (int i = 0; i < 8; i++)
#pragma unroll
        for (int j = 0; j < 8; j++) acc[i][j] = 0.f;

    for (int kc = 0; kc < 4; kc++) {            // K chunks of 32
        for (int ii = 0; ii < 4; ii++) {
            int idx = t + 256 * ii;             // 0..1023 -> 128 rows x 8 float4
            int r = idx >> 3, c4 = idx & 7;
            {   // A chunk (struct_nodes)
                int grow = b * NP + r0t + r;
                float sc = rnan[grow];
                float f0, f1, f2, f3;
                if (flag) {
                    const unsigned* src = (const unsigned*)anr + ((grow * DIMD + kc * 32 + c4 * 4) >> 1);
                    unsigned w0 = src[0], w1 = src[1];
                    f0 = bf2f_lo(w0); f1 = bf2f_hi(w0); f2 = bf2f_lo(w1); f3 = bf2f_hi(w1);
                } else {
                    float4 v = *((const float4*)((const float*)anr + grow * DIMD + kc * 32 + c4 * 4));
                    f0 = v.x; f1 = v.y; f2 = v.z; f3 = v.w;
                }
                As[r][c4 * 4 + 0] = f0 * sc; As[r][c4 * 4 + 1] = f1 * sc;
                As[r][c4 * 4 + 2] = f2 * sc; As[r][c4 * 4 + 3] = f3 * sc;
            }
            {   // B chunk (seq_tokens)
                int grow = b * NP + c0t + r;
                float sc = rnbn[grow];
                float f0, f1, f2, f3;
                if (flag) {
                    const unsigned* src = (const unsigned*)bnr + ((grow * DIMD + kc * 32 + c4 * 4) >> 1);
                    unsigned w0 = src[0], w1 = src[1];
                    f0 = bf2f_lo(w0); f1 = bf2f_hi(w0); f2 = bf2f_lo(w1); f3 = bf2f_hi(w1);
                } else {
                    float4 v = *((const float4*)((const float*)bnr + grow * DIMD + kc * 32 + c4 * 4));
                    f0 = v.x; f1 = v.y; f2 = v.z; f3 = v.w;
                }
                Bs[r][c4 * 4 + 0] = f0 * sc; Bs[r][c4 * 4 + 1] = f1 * sc;
                Bs[r][c4 * 4 + 2] = f2 * sc; Bs[r][c4 * 4 + 3] = f3 * sc;
            }
        }
        __syncthreads();
        for (int kk = 0; kk < 32; kk++) {
            float av[8], bv[8];
#pragma unroll
            for (int i = 0; i < 8; i++) av[i] = As[tr * 8 + i][kk];
#pragma unroll
            for (int j = 0; j < 8; j++) bv[j] = Bs[tc * 8 + j][kk];
#pragma unroll
            for (int i = 0; i < 8; i++)
#pragma unroll
                for (int j = 0; j < 8; j++) acc[i][j] += av[i] * bv[j];
        }
        __syncthreads();
    }
#pragma unroll
    for (int i = 0; i < 8; i++) {
        int grow = b * NP + r0t + tr * 8 + i;
        unsigned short h[8];
#pragma unroll
        for (int j = 0; j < 8; j++) h[j] = f2bf(expf(acc[i][j] * 10.0f));   // exp(sim/REG)
        uint4 pk;
        pk.x = (unsigned)h[0] | ((unsigned)h[1] << 16);
        pk.y = (unsigned)h[2] | ((unsigned)h[3] << 16);
        pk.z = (unsigned)h[4] | ((unsigned)h[5] << 16);
        pk.w = (unsigned)h[6] | ((unsigned)h[7] << 16);
        *((uint4*)(p0 + ((size_t)grow * NP + c0t + tc * 8))) = pk;
    }
}

// ---------- exchange primitives ----------
// Dual-write: plain store -> lands in this XCD's L2 (fast path for same-XCD partners);
// agent-scope relaxed atomic -> Infinity Cache (the proven, placement-independent path).
__device__ __forceinline__ void store_dual(unsigned* l2p, unsigned* ifp, unsigned v) {
    *l2p = v;
    __hip_atomic_store(ifp, v, __ATOMIC_RELAXED, __HIP_MEMORY_SCOPE_AGENT);
}

// R12 batched polling (proven): all 8 sc0 loads issue back-to-back in ONE asm block with
// ONE waitcnt -> a round costs ~1 L2 latency. One SGPR base, one VGPR voffset = t*4+4096
// (centered), partner stride 2048B / col1 +1024B folded into 13-bit signed immediates.
// Mask-free termination: matched slots re-match (write-once per (bank,chain,slot,tag)).
// From round 2 on, additionally batch-poll the IF copy (placement-independent fallback).
__device__ __forceinline__ void poll_sums(const unsigned* crdL2, const unsigned* crdIF,
                                          unsigned tag, int t, float& r0, float& r1) {
    unsigned voff = (unsigned)(t * 4) + 4096u;
    unsigned q0, q1, q2, q3, q4, q5, q6, q7;
    for (int round = 0;; ++round) {
        asm volatile(
            "global_load_dword %0, %8, %9 offset:-4096 sc0\n\t"
            "global_load_dword %1, %8, %9 offset:-2048 sc0\n\t"
            "global_load_dword %2, %8, %9 offset:0 sc0\n\t"
            "global_load_dword %3, %8, %9 offset:2048 sc0\n\t"
            "global_load_dword %4, %8, %9 offset:-3072 sc0\n\t"
            "global_load_dword %5, %8, %9 offset:-1024 sc0\n\t"
            "global_load_dword %6, %8, %9 offset:1024 sc0\n\t"
            "global_load_dword %7, %8, %9 offset:3072 sc0\n\t"
            "s_waitcnt vmcnt(0)"
            : "=&v"(q0), "=&v"(q1), "=&v"(q2), "=&v"(q3),
              "=&v"(q4), "=&v"(q5), "=&v"(q6), "=&v"(q7)
            : "v"(voff), "s"(crdL2)
            : "memory");
        if (round >= 2) {
            // IF fallback copy, batched (8 independent agent loads, compiler-coalesced waits)
            const unsigned* pp = crdIF + t;
            unsigned b0 = __hip_atomic_load(pp +    0, __ATOMIC_RELAXED, __HIP_MEMORY_SCOPE_AGENT);
            unsigned b1 = __hip_atomic_load(pp +  512, __ATOMIC_RELAXED, __HIP_MEMORY_SCOPE_AGENT);
            unsigned b2 = __hip_atomic_load(pp + 1024, __ATOMIC_RELAXED, __HIP_MEMORY_SCOPE_AGENT);
            unsigned b3 = __hip_atomic_load(pp + 1536, __ATOMIC_RELAXED, __HIP_MEMORY_SCOPE_AGENT);
            unsigned b4 = __hip_atomic_load(pp +  256, __ATOMIC_RELAXED, __HIP_MEMORY_SCOPE_AGENT);
            unsigned b5 = __hip_atomic_load(pp +  768, __ATOMIC_RELAXED, __HIP_MEMORY_SCOPE_AGENT);
            unsigned b6 = __hip_atomic_load(pp + 1280, __ATOMIC_RELAXED, __HIP_MEMORY_SCOPE_AGENT);
            unsigned b7 = __hip_atomic_load(pp + 1792, __ATOMIC_RELAXED, __HIP_MEMORY_SCOPE_AGENT);
            if ((q0 & 0xFFFFu) != tag) q0 = b0;
            if ((q1 & 0xFFFFu) != tag) q1 = b1;
            if ((q2 & 0xFFFFu) != tag) q2 = b2;
            if ((q3 & 0xFFFFu) != tag) q3 = b3;
            if ((q4 & 0xFFFFu) != tag) q4 = b4;
            if ((q5 & 0xFFFFu) != tag) q5 = b5;
            if ((q6 & 0xFFFFu) != tag) q6 = b6;
            if ((q7 & 0xFFFFu) != tag) q7 = b7;
        }
        bool ok = ((q0 & 0xFFFFu) == tag) && ((q1 & 0xFFFFu) == tag)
               && ((q2 & 0xFFFFu) == tag) && ((q3 & 0xFFFFu) == tag)
               && ((q4 & 0xFFFFu) == tag) && ((q5 & 0xFFFFu) == tag)
               && ((q6 & 0xFFFFu) == tag) && ((q7 & 0xFFFFu) == tag);
        if (ok) break;
        if (round >= 2) __builtin_amdgcn_s_sleep(1);
    }
    r0 = __uint_as_float(q0 & 0xFFFF0000u) + __uint_as_float(q1 & 0xFFFF0000u)
       + __uint_as_float(q2 & 0xFFFF0000u) + __uint_as_float(q3 & 0xFFFF0000u);
    r1 = __uint_as_float(q4 & 0xFFFF0000u) + __uint_as_float(q5 & 0xFFFF0000u)
       + __uint_as_float(q6 & 0xFFFF0000u) + __uint_as_float(q7 & 0xFFFF0000u);
}

// ---------- persistent Sinkhorn: dual-chain, 4 blocks/example, XCD-local fast exchange ----------
// R16 structure verbatim (proven ~430us k_persist, absmax 0.0): (a) lgkmcnt-only barriers;
// (b) barriers B/D removed (audit: credU w->A->r; credV,v_sU w->C->r; v_sV w->next-A->r;
// u_s* wave-local; rewrites separated by a full barrier); (c) R12 batched 8-load
// single-waitcnt poll. Schedule per double-step: colU;A; storeU+rowV; colV; pollU;C;
// storeV+rowU; pollV. Mod-2 banks per chain. Tags 1..50; 0xAA-poisoned stale ws (0xAAAA)
// never matches a tag.
__global__ __launch_bounds__(256, 1) void k_persist(const unsigned short* __restrict__ p0,
                                                    unsigned* __restrict__ colpL2,
                                                    unsigned* __restrict__ colpIF,
                                                    float* __restrict__ outf) {
    int blk = blockIdx.x;
    int rb  = blk >> 6;         // 0..3 (partners differ by 64 in blk -> same blk%8 -> same XCD)
    int b   = blk & 63;         // example
    int rowbase = rb * 128;
    int t = threadIdx.x, w = t >> 6, lane = t & 63;

    __shared__ float credU[4][512];
    __shared__ float credV[4][512];
    __shared__ float v_sU[512];
    __shared__ float v_sV[512];
    __shared__ float u_sU[128];
    __shared__ float u_sV[128];
    __shared__ float bs[4];

    // this lane's static P0 slice: 32 rows x 8 cols packed bf16 = 128 VGPRs
    uint4 pw[32];
#pragma unroll
    for (int r = 0; r < 32; r++) {
        int row = rowbase + w * 32 + r;
        pw[r] = ((const uint4*)(p0 + (((size_t)(b << 9) + row) << 9)))[lane];
    }
    int col0 = t, col1 = t + 256;
    if (t < 128) u_sU[t] = MARG;                   // u_0 = a
    v_sV[col0] = MARG; v_sV[col1] = MARG;          // v_0 = b
    __syncthreads();

#pragma unroll 1
    for (int s = 0; s < 50; ++s) {
        unsigned tag = (unsigned)(s + 1);
        int bank = s & 1;
        // ---- 1. col pass chain U ----
        {
            float ca[8];
#pragma unroll
            for (int k = 0; k < 8; ++k) ca[k] = 0.f;
#pragma unroll
            for (int r = 0; r < 32; ++r) {
                float u_r = u_sU[w * 32 + r];
                uint4 pv = pw[r];
                ca[0] += bf2f_lo(pv.x) * u_r; ca[1] += bf2f_hi(pv.x) * u_r;
                ca[2] += bf2f_lo(pv.y) * u_r; ca[3] += bf2f_hi(pv.y) * u_r;
                ca[4] += bf2f_lo(pv.z) * u_r; ca[5] += bf2f_hi(pv.z) * u_r;
                ca[6] += bf2f_lo(pv.w) * u_r; ca[7] += bf2f_hi(pv.w) * u_r;
            }
#pragma unroll
            for (int k = 0; k < 8; ++k) credU[w][lane * 8 + k] = ca[k];
        }
        wg_barrier_lds();   // A
        // ---- 2. store U (dual, fire-and-forget), then rowpass V (local) ----
        {
            int slot = ((bank * 64 + b) * 4 + rb) << 9;                  // chain U
            float s0 = credU[0][col0] + credU[1][col0] + credU[2][col0] + credU[3][col0];
            float s1 = credU[0][col1] + credU[1][col1] + credU[2][col1] + credU[3][col1];
            store_dual(colpL2 + slot + col0, colpIF + slot + col0,
                       ((unsigned)f2bf(s0) << 16) | tag);
            store_dual(colpL2 + slot + col1, colpIF + slot + col1,
                       ((unsigned)f2bf(s1) << 16) | tag);
        }
        {   // rowpass V: u'_{2s+1} = a/(P0 v_2s) -> u_sV (wave-local)
            float vr[8];
#pragma unroll
            for (int k = 0; k < 8; ++k) vr[k] = v_sV[lane * 8 + k];
#pragma unroll
            for (int g = 0; g < 4; ++g) {
                float rp[8];
#pragma unroll
                for (int j = 0; j < 8; ++j) {
                    uint4 pv = pw[g * 8 + j];
                    rp[j] = bf2f_lo(pv.x) * vr[0] + bf2f_hi(pv.x) * vr[1]
                          + bf2f_lo(pv.y) * vr[2] + bf2f_hi(pv.y) * vr[3]
                          + bf2f_lo(pv.z) * vr[4] + bf2f_hi(pv.z) * vr[5]
                          + bf2f_lo(pv.w) * vr[6] + bf2f_hi(pv.w) * vr[7];
                }
#pragma unroll
                for (int m = 1; m < 64; m <<= 1)
#pragma unroll
                    for (int j = 0; j < 8; ++j) rp[j] += __shfl_xor(rp[j], m, 64);
                float sel = rp[0];
#pragma unroll
                for (int j = 1; j < 8; ++j) if (lane == j) sel = rp[j];
                if (lane < 8) {
                    float q = MARG / sel;
                    if (!isfinite(q)) q = MARG;
                    u_sV[w * 32 + g * 8 + lane] = q;
                }
            }
        }
        // ---- 3. col pass chain V ----
        {
            float ca[8];
#pragma unroll
            for (int k = 0; k < 8; ++k) ca[k] = 0.f;
#pragma unroll
            for (int r = 0; r < 32; ++r) {
                float u_r = u_sV[w * 32 + r];      // same-wave RAW, lgkmcnt only
                uint4 pv = pw[r];
                ca[0] += bf2f_lo(pv.x) * u_r; ca[1] += bf2f_hi(pv.x) * u_r;
                ca[2] += bf2f_lo(pv.y) * u_r; ca[3] += bf2f_hi(pv.y) * u_r;
                ca[4] += bf2f_lo(pv.z) * u_r; ca[5] += bf2f_hi(pv.z) * u_r;
                ca[6] += bf2f_lo(pv.w) * u_r; ca[7] += bf2f_hi(pv.w) * u_r;
            }
#pragma unroll
            for (int k = 0; k < 8; ++k) credV[w][lane * 8 + k] = ca[k];
        }
        // (barrier B removed: credV/v_sU readers are all behind barrier C)
        // ---- 4. poll chain U -> v_sU ----
        {
            int base = ((bank * 64 + b) * 4) << 9;                       // chain U
            float r0, r1;
            poll_sums(colpL2 + base, colpIF + base, tag, t, r0, r1);
            float q0 = MARG / r0; if (!isfinite(q0)) q0 = MARG;
            float q1 = MARG / r1; if (!isfinite(q1)) q1 = MARG;
            v_sU[col0] = q0;
            v_sU[col1] = q1;
        }
        wg_barrier_lds();   // C
        // ---- 5. store V (dual), then rowpass U (local) ----
        {
            int slot = (((2 + bank) * 64 + b) * 4 + rb) << 9;            // chain V
            float s0 = credV[0][col0] + credV[1][col0] + credV[2][col0] + credV[3][col0];
            float s1 = credV[0][col1] + credV[1][col1] + credV[2][col1] + credV[3][col1];
            store_dual(colpL2 + slot + col0, colpIF + slot + col0,
                       ((unsigned)f2bf(s0) << 16) | tag);
            store_dual(colpL2 + slot + col1, colpIF + slot + col1,
                       ((unsigned)f2bf(s1) << 16) | tag);
        }
        {   // rowpass U: u_{2s+2} = a/(P0 v'_{2s+1}) -> u_sU (wave-local)
            float vr[8];
#pragma unroll
            for (int k = 0; k < 8; ++k) vr[k] = v_sU[lane * 8 + k];
#pragma unroll
            for (int g = 0; g < 4; ++g) {
                float rp[8];
#pragma unroll
                for (int j = 0; j < 8; ++j) {
                    uint4 pv = pw[g * 8 + j];
                    rp[j] = bf2f_lo(pv.x) * vr[0] + bf2f_hi(pv.x) * vr[1]
                          + bf2f_lo(pv.y) * vr[2] + bf2f_hi(pv.y) * vr[3]
                          + bf2f_lo(pv.z) * vr[4] + bf2f_hi(pv.z) * vr[5]
                          + bf2f_lo(pv.w) * vr[6] + bf2f_hi(pv.w) * vr[7];
                }
#pragma unroll
                for (int m = 1; m < 64; m <<= 1)
#pragma unroll
                    for (int j = 0; j < 8; ++j) rp[j] += __shfl_xor(rp[j], m, 64);
                float sel = rp[0];
#pragma unroll
                for (int j = 1; j < 8; ++j) if (lane == j) sel = rp[j];
                if (lane < 8) {
                    float q = MARG / sel;
                    if (!isfinite(q)) q = MARG;
                    u_sU[w * 32 + g * 8 + lane] = q;
                }
            }
        }
        // ---- 6. poll chain V -> v_sV ----
        {
            int base = (((2 + bank) * 64 + b) * 4) << 9;                 // chain V
            float r0, r1;
            poll_sums(colpL2 + base, colpIF + base, tag, t, r0, r1);
            float q0 = MARG / r0; if (!isfinite(q0)) q0 = MARG;
            float q1 = MARG / r1; if (!isfinite(q1)) q1 = MARG;
            v_sV[col0] = q0;
            v_sV[col1] = q1;
        }
        // (barrier D removed: v_sV readers are behind next iteration's barrier A,
        //  or the post-loop barrier below)
    }
    wg_barrier_lds();   // post-loop: v_sV cross-thread reads in the final contraction

    // ---- final contraction: u_100 (u_sU) x v_100 (v_sV) ; C = -0.1*log(P0) ----
    float vr[8];
#pragma unroll
    for (int k = 0; k < 8; ++k) vr[k] = v_sV[lane * 8 + k];
    float acc = 0.f;
#pragma unroll
    for (int r = 0; r < 32; ++r) {
        float u_r = u_sU[w * 32 + r];
        uint4 pv = pw[r];
        float f[8];
        f[0] = bf2f_lo(pv.x); f[1] = bf2f_hi(pv.x);
        f[2] = bf2f_lo(pv.y); f[3] = bf2f_hi(pv.y);
        f[4] = bf2f_lo(pv.z); f[5] = bf2f_hi(pv.z);
        f[6] = bf2f_lo(pv.w); f[7] = bf2f_hi(pv.w);
#pragma unroll
        for (int k = 0; k < 8; ++k) {
            float p = f[k];
            acc += u_r * p * vr[k] * (-0.1f) * logf(p);
        }
    }
    acc = wred64(acc);
    if (lane == 0) bs[w] = acc;
    __syncthreads();
    if (t == 0) {
        float c = (bs[0] + bs[1] + bs[2] + bs[3]) * (1.0f / 64.0f);   // /B
        atomicAdd(&outf[1], c);
        atomicAdd(&outf[2], c);
    }
}

extern "C" void kernel_launch(void* const* d_in, const int* in_sizes, int n_in,
                              void* d_out, int out_size, void* d_ws, size_t ws_size,
                              hipStream_t stream) {
    const void* sg = d_in[0];
    const void* qg = d_in[1];
    const void* an = d_in[2];
    const void* bn = d_in[3];
    char* ws = (char*)d_ws;
    float* outf = (float*)d_out;                     // output dtype: float32 x3

    float* rnan      = (float*)(ws + O_RNAN);
    float* rnbn      = (float*)(ws + O_RNBN);
    unsigned* colpL2 = (unsigned*)(ws + O_COLP);     // L2-resident tagged copy
    unsigned* colpIF = (unsigned*)(ws + O_COLPIF);   // IF-resident tagged copy (fallback)
    unsigned short* p0 = (unsigned short*)(ws + O_P0);

    // R25 = R23 verbatim (proven best, 613.6us): k_rnormAB -> k_build_g (build grid +
    // embedded global-loss block) -> k_persist (R16-proven).
    k_rnormAB<<<16384, 256, 0, stream>>>(an, bn, rnan, rnbn);
    k_build_g<<<dim3(17, 64), 256, 0, stream>>>(an, bn, rnan, rnbn, sg, qg, p0, outf);
    k_persist<<<256, 256, 0, stream>>>(p0, colpL2, colpIF, outf);
}